// Round 3
// baseline (346.554 us; speedup 1.0000x reference)
//
#include <hip/hip_runtime.h>

#define NFEAT 42
#define H1 256
#define H2 128
#define H3 64
#define NB 8
#define NA 512
#define NM 100
#define TA 4   // atoms per MLP block (grid 1024 -> 4 blocks/CU)

__device__ __forceinline__ float sigmoidf(float z) {
    return 1.0f / (1.0f + __expf(-z));
}

// -------- Kernel 0: transpose weights (write-coalesced) --------
__global__ __launch_bounds__(256) void transpose_weights(
    const float* __restrict__ W0, const float* __restrict__ W1, const float* __restrict__ W2,
    float* __restrict__ W0T, float* __restrict__ W1T, float* __restrict__ W2T)
{
    int i = blockIdx.x * 256 + threadIdx.x;
    if (i < H1 * NFEAT) {           // W0T[k][f] = W0[f][k]
        int k = i / NFEAT, f = i - k * NFEAT;
        W0T[i] = W0[f * H1 + k];
    }
    if (i < H2 * H1) {              // W1T[j][k] = W1[k][j]
        int j = i >> 8, k = i & 255;
        W1T[i] = W1[k * H2 + j];
    }
    if (i < H3 * H2) {              // W2T[k][j] = W2[j][k]
        int k = i >> 7, j = i & 127;
        W2T[i] = W2[j * H3 + k];
    }
}

// -------- Kernel 1: per-4-atom MLP forward + backward (dE/dx) --------
__global__ __launch_bounds__(256) void mlp_fwd_bwd(
    const float* __restrict__ image,
    const float* __restrict__ W0, const float* __restrict__ b0,
    const float* __restrict__ W1, const float* __restrict__ b1,
    const float* __restrict__ W2, const float* __restrict__ b2,
    const float* __restrict__ W3, const float* __restrict__ b3,
    const float* __restrict__ W0T, const float* __restrict__ W1T, const float* __restrict__ W2T,
    float* __restrict__ Ei,   // [B*N]
    float* __restrict__ dE)   // [B*N, NFEAT]
{
    const int t = threadIdx.x;
    const int atom0 = blockIdx.x * TA;

    __shared__ __align__(16) float sx[TA][NFEAT + 2];   // pad to 44 for alignment
    __shared__ __align__(16) float sh1[TA][H1];
    __shared__ __align__(16) float sh2[TA][H2];
    __shared__ __align__(16) float sh3[TA][H3];
    __shared__ __align__(16) float sd3[TA][H3];
    __shared__ __align__(16) float sd2[TA][H2];
    __shared__ __align__(16) float sd1[TA][H1];

    for (int i = t; i < TA * NFEAT; i += 256) {
        int a = i / NFEAT, f = i - a * NFEAT;
        sx[a][f] = image[(atom0 + a) * NFEAT + f];
    }
    __syncthreads();

    // ---- layer 0: 42 -> 256, sigmoid (thread = out neuron j=t, 4 atoms) ----
    {
        float acc[TA] = {0.f, 0.f, 0.f, 0.f};
        for (int kk = 0; kk < 10; ++kk) {   // k = 0..39
            float w0_ = W0[(4 * kk + 0) * H1 + t];
            float w1_ = W0[(4 * kk + 1) * H1 + t];
            float w2_ = W0[(4 * kk + 2) * H1 + t];
            float w3_ = W0[(4 * kk + 3) * H1 + t];
            #pragma unroll
            for (int a = 0; a < TA; ++a) {
                float4 h = ((const float4*)sx[a])[kk];
                acc[a] += h.x * w0_ + h.y * w1_ + h.z * w2_ + h.w * w3_;
            }
        }
        float wa = W0[40 * H1 + t], wb = W0[41 * H1 + t];
        float bb = b0[t];
        #pragma unroll
        for (int a = 0; a < TA; ++a) {
            acc[a] += sx[a][40] * wa + sx[a][41] * wb;
            sh1[a][t] = sigmoidf(acc[a] + bb);
        }
    }
    __syncthreads();

    // ---- layer 1: 256 -> 128, sigmoid (j = t&127, 2 atoms per thread) ----
    {
        const int j = t & 127, a0 = (t >> 7) * 2;
        float acc[2] = {0.f, 0.f};
        for (int kk = 0; kk < H1 / 4; ++kk) {
            float w0_ = W1[(4 * kk + 0) * H2 + j];
            float w1_ = W1[(4 * kk + 1) * H2 + j];
            float w2_ = W1[(4 * kk + 2) * H2 + j];
            float w3_ = W1[(4 * kk + 3) * H2 + j];
            #pragma unroll
            for (int a = 0; a < 2; ++a) {
                float4 h = ((const float4*)sh1[a0 + a])[kk];
                acc[a] += h.x * w0_ + h.y * w1_ + h.z * w2_ + h.w * w3_;
            }
        }
        float bb = b1[j];
        #pragma unroll
        for (int a = 0; a < 2; ++a) sh2[a0 + a][j] = sigmoidf(acc[a] + bb);
    }
    __syncthreads();

    // ---- layer 2: 128 -> 64, sigmoid (j = t&63, 1 atom per thread) ----
    {
        const int j = t & 63, a = t >> 6;
        float acc = 0.f;
        for (int kk = 0; kk < H2 / 4; ++kk) {
            float w0_ = W2[(4 * kk + 0) * H3 + j];
            float w1_ = W2[(4 * kk + 1) * H3 + j];
            float w2_ = W2[(4 * kk + 2) * H3 + j];
            float w3_ = W2[(4 * kk + 3) * H3 + j];
            float4 h = ((const float4*)sh2[a])[kk];
            acc += h.x * w0_ + h.y * w1_ + h.z * w2_ + h.w * w3_;
        }
        sh3[a][j] = sigmoidf(acc + b2[j]);
    }
    __syncthreads();

    // ---- output layer 64 -> 1 (linear) + sd3 (wave w = atom w) ----
    {
        const int lane = t & 63, a = t >> 6;
        float w = W3[lane];
        float h = sh3[a][lane];
        sd3[a][lane] = w * h * (1.f - h);
        float v = w * h;
        #pragma unroll
        for (int off = 32; off > 0; off >>= 1) v += __shfl_down(v, off, 64);
        if (lane == 0) Ei[atom0 + a] = v + b3[0];
    }
    __syncthreads();

    // ---- bwd: d2 = (W2 @ d3) * h2' (j = t&127, 2 atoms) ----
    {
        const int j = t & 127, a0 = (t >> 7) * 2;
        float acc[2] = {0.f, 0.f};
        for (int kk = 0; kk < H3 / 4; ++kk) {
            float w0_ = W2T[(4 * kk + 0) * H2 + j];
            float w1_ = W2T[(4 * kk + 1) * H2 + j];
            float w2_ = W2T[(4 * kk + 2) * H2 + j];
            float w3_ = W2T[(4 * kk + 3) * H2 + j];
            #pragma unroll
            for (int a = 0; a < 2; ++a) {
                float4 d = ((const float4*)sd3[a0 + a])[kk];
                acc[a] += d.x * w0_ + d.y * w1_ + d.z * w2_ + d.w * w3_;
            }
        }
        #pragma unroll
        for (int a = 0; a < 2; ++a) {
            float h = sh2[a0 + a][j];
            sd2[a0 + a][j] = acc[a] * h * (1.f - h);
        }
    }
    __syncthreads();

    // ---- bwd: d1 = (W1 @ d2) * h1' (k = t, 4 atoms) ----
    {
        float acc[TA] = {0.f, 0.f, 0.f, 0.f};
        for (int jj = 0; jj < H2 / 4; ++jj) {
            float w0_ = W1T[(4 * jj + 0) * H1 + t];
            float w1_ = W1T[(4 * jj + 1) * H1 + t];
            float w2_ = W1T[(4 * jj + 2) * H1 + t];
            float w3_ = W1T[(4 * jj + 3) * H1 + t];
            #pragma unroll
            for (int a = 0; a < TA; ++a) {
                float4 d = ((const float4*)sd2[a])[jj];
                acc[a] += d.x * w0_ + d.y * w1_ + d.z * w2_ + d.w * w3_;
            }
        }
        #pragma unroll
        for (int a = 0; a < TA; ++a) {
            float h = sh1[a][t];
            sd1[a][t] = acc[a] * h * (1.f - h);
        }
    }
    __syncthreads();

    // ---- bwd: dE/dx = W0 @ d1 (f = t&63 < 42, 1 atom) ----
    {
        const int f = t & 63, a = t >> 6;
        if (f < NFEAT) {
            float acc = 0.f;
            for (int kk = 0; kk < H1 / 4; ++kk) {
                float w0_ = W0T[(4 * kk + 0) * NFEAT + f];
                float w1_ = W0T[(4 * kk + 1) * NFEAT + f];
                float w2_ = W0T[(4 * kk + 2) * NFEAT + f];
                float w3_ = W0T[(4 * kk + 3) * NFEAT + f];
                float4 d = ((const float4*)sd1[a])[kk];
                acc += d.x * w0_ + d.y * w1_ + d.z * w2_ + d.w * w3_;
            }
            dE[(atom0 + a) * NFEAT + f] = acc;
        }
    }
}

// -------- Kernel 2: Etot[b] = sum_i Ei[b,i] --------
__global__ __launch_bounds__(256) void etot_kernel(const float* __restrict__ Ei,
                                                   float* __restrict__ Etot)
{
    const int b = blockIdx.x;
    const int t = threadIdx.x;
    float v = Ei[b * NA + t] + Ei[b * NA + t + 256];
    __shared__ float red[4];
    #pragma unroll
    for (int off = 32; off > 0; off >>= 1) v += __shfl_down(v, off, 64);
    if ((t & 63) == 0) red[t >> 6] = v;
    __syncthreads();
    if (t == 0) Etot[b] = red[0] + red[1] + red[2] + red[3];
}

// -------- Kernel 3: Force via float4-coalesced dfeat stream (2 streams in flight) --------
__global__ __launch_bounds__(256) void force_kernel(
    const float* __restrict__ dfeat,     // [B,N,M,NFEAT,3] = [bi][100][126]
    const int*   __restrict__ neighbor,  // [B,N,M]
    const float* __restrict__ dE,        // [B,N,NFEAT]
    float* __restrict__ Force)           // [B,N,3]
{
    const int bi = blockIdx.x;
    const int b  = bi >> 9;
    const int t  = threadIdx.x;

    __shared__ int   s_nb[NM];
    __shared__ float s_dE[104 * NFEAT];   // rows 100..103 zero-padded
    __shared__ float s_part[1008];
    __shared__ float s_red[126];

    if (t < NM) s_nb[t] = neighbor[bi * NM + t];
    for (int i = t; i < 4 * NFEAT; i += 256) s_dE[NM * NFEAT + i] = 0.f;
    __syncthreads();

    for (int i = t; i < NM * NFEAT; i += 256) {
        int m = i / NFEAT, f = i - m * NFEAT;
        int n = s_nb[m];
        s_dE[i] = (n > 0) ? dE[((b << 9) + n - 1) * NFEAT + f] : 0.f;
    }
    __syncthreads();

    if (t < 252) {
        const int e4 = 4 * t;
        int off[4];
        #pragma unroll
        for (int c = 0; c < 4; ++c) {
            int ee = e4 + c;
            int r  = ee / 126;            // row within 8-row group
            int e  = ee - r * 126;        // element within row (f*3+d)
            off[c] = r * NFEAT + e / 3;
        }
        const float* base = dfeat + (size_t)bi * (NM * NFEAT * 3);
        float acc[4] = {0.f, 0.f, 0.f, 0.f};

        // rows 0..95 as two independent streams (m0 and m0+48)
        for (int m0 = 0; m0 < 48; m0 += 8) {
            float4 vA = *(const float4*)(base + m0 * 126 + e4);
            float4 vB = *(const float4*)(base + (m0 + 48) * 126 + e4);
            const float* sdA = s_dE + m0 * NFEAT;
            const float* sdB = s_dE + (m0 + 48) * NFEAT;
            acc[0] += vA.x * sdA[off[0]] + vB.x * sdB[off[0]];
            acc[1] += vA.y * sdA[off[1]] + vB.y * sdB[off[1]];
            acc[2] += vA.z * sdA[off[2]] + vB.z * sdB[off[2]];
            acc[3] += vA.w * sdA[off[3]] + vB.w * sdB[off[3]];
        }
        {   // tail rows 96..103 (rows >= 100 hit zero-padded s_dE; the float4
            // over-read stays inside dfeat except for the global last block)
            const int m0 = 96;
            float vv[4];
            if (bi != NB * NA - 1) {
                float4 v = *(const float4*)(base + m0 * 126 + e4);
                vv[0] = v.x; vv[1] = v.y; vv[2] = v.z; vv[3] = v.w;
            } else {
                #pragma unroll
                for (int c = 0; c < 4; ++c) {
                    int r = (e4 + c) / 126;
                    vv[c] = (m0 + r < NM) ? base[m0 * 126 + e4 + c] : 0.f;
                }
            }
            const float* sd = s_dE + m0 * NFEAT;
            #pragma unroll
            for (int c = 0; c < 4; ++c) acc[c] += vv[c] * sd[off[c]];
        }
        #pragma unroll
        for (int c = 0; c < 4; ++c) s_part[e4 + c] = acc[c];
    }
    __syncthreads();

    if (t < 126) {
        float s = 0.f;
        #pragma unroll
        for (int r = 0; r < 8; ++r) s += s_part[r * 126 + t];
        s_red[t] = s;
    }
    __syncthreads();

    if (t < 3) {
        float s = 0.f;
        #pragma unroll
        for (int f = 0; f < NFEAT; ++f) s += s_red[f * 3 + t];
        Force[bi * 3 + t] = s;
    }
}

extern "C" void kernel_launch(void* const* d_in, const int* in_sizes, int n_in,
                              void* d_out, int out_size, void* d_ws, size_t ws_size,
                              hipStream_t stream) {
    const float* image    = (const float*)d_in[0];
    const float* dfeat    = (const float*)d_in[1];
    const int*   neighbor = (const int*)  d_in[2];
    const float* W0 = (const float*)d_in[3];
    const float* b0 = (const float*)d_in[4];
    const float* W1 = (const float*)d_in[5];
    const float* b1 = (const float*)d_in[6];
    const float* W2 = (const float*)d_in[7];
    const float* b2 = (const float*)d_in[8];
    const float* W3 = (const float*)d_in[9];
    const float* b3 = (const float*)d_in[10];

    float* out   = (float*)d_out;
    float* Etot  = out;                    // [8]
    float* Ei    = out + NB;               // [8*512]
    float* Force = out + NB + NB * NA;     // [8*512*3]

    float* dE  = (float*)d_ws;             // [4096*42]
    float* W0T = dE  + NB * NA * NFEAT;    // [256*42]
    float* W1T = W0T + H1 * NFEAT;         // [128*256]
    float* W2T = W1T + H2 * H1;            // [64*128]

    transpose_weights<<<(H1 * H2 + 255) / 256, 256, 0, stream>>>(W0, W1, W2, W0T, W1T, W2T);
    mlp_fwd_bwd<<<(NB * NA) / TA, 256, 0, stream>>>(image, W0, b0, W1, b1, W2, b2, W3, b3,
                                                    W0T, W1T, W2T, Ei, dE);
    etot_kernel<<<NB, 256, 0, stream>>>(Ei, Etot);
    force_kernel<<<NB * NA, 256, 0, stream>>>(dfeat, neighbor, dE, Force);
}